// Round 7
// baseline (21766.628 us; speedup 1.0000x reference)
//
#include <hip/hip_runtime.h>
#include <math.h>

#define T_STEPS 4096
#define HID     2048
#define MOD     256
#define INSZ    1024

#define NBLK   16        // blocks in recurrence kernel (2 per XCD)
#define NTHR   512       // threads per block (8 waves = 2 waves/SIMD)
#define RPM    16        // rest rows per module owned by each block
#define NSLOT7 (7 * MOD) // 1792 rest-row packet slots per bank
#define NPART  (NBLK * MOD) // 4096 partial packet slots per bank

// ---------------------------------------------------------------------------
// Agent-scope (device-coherent) helpers: serviced at the LLC, bypassing the
// non-coherent per-XCD L2s. Packets are self-validating (tag<<32 | fp32
// bits), so relaxed ordering suffices and the poll IS the data load.
// ---------------------------------------------------------------------------
static __device__ __forceinline__ unsigned long long agent_load_u64(
        const unsigned long long* p) {
    return __hip_atomic_load((unsigned long long*)p, __ATOMIC_RELAXED,
                             __HIP_MEMORY_SCOPE_AGENT);
}
static __device__ __forceinline__ void agent_store_u64(
        unsigned long long* p, unsigned long long v) {
    __hip_atomic_store(p, v, __ATOMIC_RELAXED, __HIP_MEMORY_SCOPE_AGENT);
}

// ---------------------------------------------------------------------------
// Kernel 1 (unchanged): U = x @ W_ih^T + (b_ih + b_hh) into out[t, i].
// ---------------------------------------------------------------------------
#define BM 128
#define BN 128
#define BK 8

__global__ __launch_bounds__(256) void gemm_u(
    const float* __restrict__ x, const float* __restrict__ Wih,
    const float* __restrict__ bih, const float* __restrict__ bhh,
    float* __restrict__ out)
{
    __shared__ float As[BK][BM];
    __shared__ float Bs[BK][BN];

    const int tid = threadIdx.x;
    const int t0 = blockIdx.y * BM;
    const int i0 = blockIdx.x * BN;
    const int tx = tid & 15;
    const int ty = tid >> 4;
    const int arow = tid >> 1;
    const int acol = (tid & 1) * 4;

    float acc[8][8];
#pragma unroll
    for (int a = 0; a < 8; ++a)
#pragma unroll
        for (int b = 0; b < 8; ++b) acc[a][b] = 0.0f;

    for (int k0 = 0; k0 < INSZ; k0 += BK) {
        float4 av = *(const float4*)(x   + (size_t)(t0 + arow) * INSZ + k0 + acol);
        float4 bv = *(const float4*)(Wih + (size_t)(i0 + arow) * INSZ + k0 + acol);
        __syncthreads();
        As[acol + 0][arow] = av.x; As[acol + 1][arow] = av.y;
        As[acol + 2][arow] = av.z; As[acol + 3][arow] = av.w;
        Bs[acol + 0][arow] = bv.x; Bs[acol + 1][arow] = bv.y;
        Bs[acol + 2][arow] = bv.z; Bs[acol + 3][arow] = bv.w;
        __syncthreads();
#pragma unroll
        for (int kk = 0; kk < BK; ++kk) {
            float a[8], b[8];
            *(float4*)&a[0] = *(const float4*)&As[kk][ty * 8];
            *(float4*)&a[4] = *(const float4*)&As[kk][ty * 8 + 4];
            *(float4*)&b[0] = *(const float4*)&Bs[kk][tx * 8];
            *(float4*)&b[4] = *(const float4*)&Bs[kk][tx * 8 + 4];
#pragma unroll
            for (int ri = 0; ri < 8; ++ri)
#pragma unroll
                for (int ci = 0; ci < 8; ++ci)
                    acc[ri][ci] = fmaf(a[ri], b[ci], acc[ri][ci]);
        }
    }

    float bias[8];
#pragma unroll
    for (int ci = 0; ci < 8; ++ci) {
        int i = i0 + tx * 8 + ci;
        bias[ci] = bih[i] + bhh[i];
    }
#pragma unroll
    for (int ri = 0; ri < 8; ++ri) {
        int t = t0 + ty * 8 + ri;
#pragma unroll
        for (int ci = 0; ci < 8; ++ci) {
            int i = i0 + tx * 8 + ci;
            out[(size_t)t * HID + i] = acc[ri][ci] + bias[ci];
        }
    }
}

// ---------------------------------------------------------------------------
// Kernel 2: replicated-module-0 recurrence, MERGED single exchange / 2 steps.
// 16 blocks x 512 threads.
//
// Model from R0-R6: each cross-XCD visibility round trip ~3500 cyc; duration
// ~= #serialized-exchanges x RT-chain. R4 had TWO exchanges per 2 steps
// (h then C). Here the C exchange is folded into the h exchange: the block
// that computes h-rows owns those COLUMNS of the dC sum, so it publishes
// per-block partials  partial_b[i] = sum_{c in owned} W0rest[i][c]*delta[c]
// in the same round. Consumers poll h-packets + partials together, then
// C(t) = C(t-2) + sum_b partial_b. Odd steps: ZERO communication.
// => 2048 exchanges total (was 4096), poll-is-data protocol (fastest).
//
// Slot safety (double-banked by (t>>1)&1): publish(t+4) by X requires X
// passed poll(t+2); poll(t+2) requires all published(t+2); publish(t+2) by Y
// happens after Y's absorb(t). So every block consumed bank(t) before any
// overwrite at t+4. Skew < 2.5 steps => 3-deep out-row ring race-free, and
// out-row reuse (U read at step t from row t, h written to row t-3) safe.
//
// C vintage chain: even t absorbs C(t) into lds_C; odd t+1 module-0 uses
// C(t); even t+2 module-0 uses lds_C (= C(t+1) = C(t), h_rest frozen at odd
// steps). Partial sums are computed in the same order by every block =>
// module-0 replicas stay bit-identical.
// ---------------------------------------------------------------------------
__global__ __launch_bounds__(NTHR)
__attribute__((amdgpu_waves_per_eu(2, 2)))
void cwrnn_rec(
    float* __restrict__ out, const float* __restrict__ Whh,
    unsigned long long* __restrict__ comm)
{
    const int tid   = threadIdx.x;
    const int b     = blockIdx.x;        // 0..15
    const int lane  = tid & 63;
    const int wave  = tid >> 6;          // 0..7
    const int r8    = tid >> 4;          // row group: rows 8*r8..8*r8+7
    const int c16   = tid & 15;          // col group: cols 16*c16..16*c16+15
    const int rsel  = c16 & 7;
    const int myrow = 8 * r8 + rsel;     // row this thread finalizes (c16<8)

    unsigned long long* comm_h = comm;              // [2][NSLOT7] h banks
    unsigned long long* comm_p = comm + 2 * NSLOT7; // [2][NPART] partial banks

    __shared__ __align__(16) float lds_h[HID];        // replicated full h
    __shared__ __align__(16) float h0p[320];          // padded h0: word = e + (e>>4)*4
    __shared__ __align__(16) float lds_C[MOD];        // replicated C
    __shared__ __align__(16) float lds_u0[MOD];       // U0[t] (prefetched)
    __shared__ __align__(16) float lds_ur[112];       // U[t] for owned rest rows
    __shared__ __align__(16) float ldelta[112];       // owned-col deltas
    __shared__ __align__(16) float lhnew[112];        // owned-row new h values
    __shared__ __align__(16) float lds_ps[NTHR];      // partial half-sums
    __shared__ __align__(16) float lds_ring[3][128];  // delayed out slice
    __shared__ __align__(16) float w0pT[112][256];    // W0rest^T owned cols (114KB)

    // ---- W00 fragment in registers/AGPRs: rows 8r8..+7, cols 16c16..+15
    float4 w00[8][4];
#pragma unroll
    for (int rr = 0; rr < 8; ++rr) {
        const float* wr = Whh + (size_t)(8 * r8 + rr) * HID + 16 * c16;
#pragma unroll
        for (int i = 0; i < 4; ++i) w00[rr][i] = *(const float4*)(wr + 4 * i);
    }

    // ---- load W0rest^T for owned cols: w0pT[c][i] = Whh[i][m*256+16b+e],
    //      c = (m-1)*16+e. Column gather (one-time init cost).
    for (int idx = tid; idx < 112 * 256; idx += NTHR) {
        const int c = idx >> 8, i = idx & 255;
        const int m = 1 + (c >> 4), e = c & 15;
        w0pT[c][i] = Whh[(size_t)i * HID + m * MOD + RPM * b + e];
    }

    // ---- zero init (h(0) = 0, C(0) = 0)
    for (int i = tid; i < HID; i += NTHR) lds_h[i] = 0.f;
    if (tid < 320) h0p[tid] = 0.f;
    if (tid < MOD) lds_C[tid] = 0.f;
    if (tid < 112) { lds_ur[tid] = 0.f; ldelta[tid] = 0.f; lhnew[tid] = 0.f; }
    if (tid < 384) (&lds_ring[0][0])[tid] = 0.f;

    {   // preload U(1) = gemm row 0, cols [0,256)
        float4 u4 = make_float4(0.f, 0.f, 0.f, 0.f);
        if (tid < 64) u4 = *(const float4*)(out + 4 * tid);
        __syncthreads();
        if (tid < 64) *(float4*)(lds_u0 + 4 * tid) = u4;
        __syncthreads();
    }

    for (int t = 1; t <= T_STEPS; ++t) {
        const bool ev = (t & 1) == 0;
        const int ctz = __builtin_ctz(t);
        const int j   = ev ? (ctz < 7 ? ctz : 7) : 0;  // active rest modules 1..j
        const int nslot = j * MOD;
        const int par   = (t >> 1) & 1;
        const int bank  = par * NSLOT7;
        const int pbank = par * NPART;
        const unsigned long long tagbits =
            ((unsigned long long)(unsigned)t) << 32;

        // ---------- early phase: U value, delayed emission, U prefetch issue
        const float uval = lds_u0[myrow];
        if (t >= 3 && tid < 32) {   // emit out row t-3 = h(t-2), slot (t+1)%3
            float4 e4 = *(const float4*)(&lds_ring[(t + 1) % 3][4 * tid]);
            *(float4*)(out + (size_t)(t - 3) * HID + 128 * b + 4 * tid) = e4;
        }
        float4 pf0 = make_float4(0.f, 0.f, 0.f, 0.f);
        float4 pfr = make_float4(0.f, 0.f, 0.f, 0.f);
        if (t < T_STEPS) {
            if (tid < 64)   // U0 for step t+1 (gemm row t)
                pf0 = *(const float4*)(out + (size_t)t * HID + 4 * tid);
            if (!ev && tid >= 64 && tid < 64 + 28) {  // rest-U for even t+1
                const int idx = tid - 64, mm = idx >> 2, dd = idx & 3;
                pfr = *(const float4*)(out + (size_t)t * HID
                                       + (mm + 1) * MOD + RPM * b + 4 * dd);
            }
        }

        if (ev) {
            // ---- GEMV owned active rows (full 2048-dot); stash hv + delta
            for (int ridx = wave; ridx < RPM * j; ridx += 8) {
                const int m = 1 + (ridx >> 4);
                const int e = ridx & 15;
                const float* wrow = Whh + (size_t)(m * MOD + RPM * b + e) * HID;
                float4 wv[8];
#pragma unroll
                for (int k = 0; k < 8; ++k)
                    wv[k] = *(const float4*)(wrow + 4 * lane + 256 * k);
                float sx = 0.f, sy = 0.f, sz = 0.f, sw = 0.f;
#pragma unroll
                for (int k = 0; k < 8; ++k) {
                    const float4 hv = *(const float4*)(lds_h + 4 * lane + 256 * k);
                    sx = fmaf(wv[k].x, hv.x, sx);
                    sy = fmaf(wv[k].y, hv.y, sy);
                    sz = fmaf(wv[k].z, hv.z, sz);
                    sw = fmaf(wv[k].w, hv.w, sw);
                }
                float acc = (sx + sy) + (sz + sw);
#pragma unroll
                for (int off = 32; off; off >>= 1)
                    acc += __shfl_xor(acc, off, 64);
                if (lane == 0) {
                    const float hv = tanhf(lds_ur[(m - 1) * RPM + e] + acc);
                    lhnew[ridx]  = hv;
                    ldelta[ridx] = hv - lds_h[m * MOD + RPM * b + e];
                }
            }
            __syncthreads();                               // B1 (ldelta ready)

            // ---- publish: partials (tid<256) + h packets (tid>=256)
            if (tid < 256) {
                float pp = 0.f;
                for (int c = 0; c < 16 * j; ++c)
                    pp = fmaf(w0pT[c][tid], ldelta[c], pp);
                agent_store_u64(comm_p + pbank + tid * NBLK + b,
                    tagbits | (unsigned long long)__float_as_uint(pp));
            } else {
                const int s = tid - 256;
                if (s < 16 * j) {
                    const int m = 1 + (s >> 4), e = s & 15;
                    agent_store_u64(comm_h + bank + (m - 1) * MOD + RPM * b + e,
                        tagbits | (unsigned long long)__float_as_uint(lhnew[s]));
                }
            }

            // ---- issue merged poll loads (fly under the W00 MAC)
            const int pi = tid >> 1, ph = (tid & 1) * 8;
            unsigned long long pv[8];
#pragma unroll
            for (int k = 0; k < 8; ++k)
                pv[k] = agent_load_u64(comm_p + pbank + pi * NBLK + ph + k);
            unsigned long long hvp[4] = {0, 0, 0, 0};
#pragma unroll
            for (int k = 0; k < 4; ++k)
                if (tid + 512 * k < nslot)
                    hvp[k] = agent_load_u64(comm_h + bank + tid + 512 * k);

            // ---- module-0 MAC: W00 . h0(t-1)
            float a[8];
#pragma unroll
            for (int rr = 0; rr < 8; ++rr) a[rr] = 0.f;
#pragma unroll
            for (int i = 0; i < 4; ++i) {
                const float4 hv = *(const float4*)(h0p + 20 * c16 + 4 * i);
#pragma unroll
                for (int rr = 0; rr < 8; ++rr) {
                    a[rr] = fmaf(w00[rr][i].x, hv.x, a[rr]);
                    a[rr] = fmaf(w00[rr][i].y, hv.y, a[rr]);
                    a[rr] = fmaf(w00[rr][i].z, hv.z, a[rr]);
                    a[rr] = fmaf(w00[rr][i].w, hv.w, a[rr]);
                }
            }
#pragma unroll
            for (int off = 1; off <= 8; off <<= 1) {
#pragma unroll
                for (int rr = 0; rr < 8; ++rr)
                    a[rr] += __shfl_xor(a[rr], off, 64);
            }
            float pre = a[0];                // static-index select (rule #20)
#pragma unroll
            for (int rr = 1; rr < 8; ++rr) pre = (rsel == rr) ? a[rr] : pre;
            // even module-0 uses C(t-2) (== C(t-1)); read BEFORE absorb
            const float hv_new = tanhf(uval + lds_C[myrow] + pre);

            // ---- finish merged poll (register-carried retry)
            {
                const unsigned need = (unsigned)t;
                for (;;) {
                    bool ok = true;
#pragma unroll
                    for (int k = 0; k < 8; ++k)
                        ok = ok && ((unsigned)(pv[k] >> 32) >= need);
#pragma unroll
                    for (int k = 0; k < 4; ++k)
                        if (tid + 512 * k < nslot)
                            ok = ok && ((unsigned)(hvp[k] >> 32) >= need);
                    if (ok) break;
#pragma unroll
                    for (int k = 0; k < 8; ++k)
                        pv[k] = agent_load_u64(comm_p + pbank + pi * NBLK + ph + k);
#pragma unroll
                    for (int k = 0; k < 4; ++k)
                        if (tid + 512 * k < nslot)
                            hvp[k] = agent_load_u64(comm_h + bank + tid + 512 * k);
                }
            }
            {   // partial half-sum -> LDS (deterministic order, all replicas)
                float ps = 0.f;
#pragma unroll
                for (int k = 0; k < 8; ++k)
                    ps += __uint_as_float((unsigned)pv[k]);
                lds_ps[tid] = ps;
            }
            __syncthreads();                               // B2 (all reads done)

            // ---- absorb: C update, h_rest replicas, module-0, ring
            if (tid < 256)
                lds_C[tid] += lds_ps[2 * tid] + lds_ps[2 * tid + 1];
            {
                const int base = 128 * b - MOD;   // ring slot base (b>=2)
#pragma unroll
                for (int k = 0; k < 4; ++k) {
                    const int s2 = tid + 512 * k;
                    if (s2 < nslot) {
                        const float v = __uint_as_float((unsigned)hvp[k]);
                        lds_h[MOD + s2] = v;
                        if (b >= 2 && s2 >= base && s2 < base + 128)
                            lds_ring[t % 3][s2 - base] = v;
                    }
                }
            }
            if (c16 < 8) {
                lds_h[myrow] = hv_new;
                h0p[myrow + (myrow >> 4) * 4] = hv_new;
                if (b < 2 && (myrow >> 7) == b)
                    lds_ring[t % 3][myrow & 127] = hv_new;
            }
            if (b >= 2 && (b >> 1) > j && tid < 32)  // slice module inactive
                *(float4*)(&lds_ring[t % 3][4 * tid]) =
                    *(const float4*)(&lds_ring[(t + 2) % 3][4 * tid]);
            if (t < T_STEPS && tid < 64)
                *(float4*)(lds_u0 + 4 * tid) = pf0;
            __syncthreads();                               // B3 (end)
        } else {
            // ---------- odd: FULLY LOCAL (no comm, no spin)
            float a[8];
#pragma unroll
            for (int rr = 0; rr < 8; ++rr) a[rr] = 0.f;
#pragma unroll
            for (int i = 0; i < 4; ++i) {
                const float4 hv = *(const float4*)(h0p + 20 * c16 + 4 * i);
#pragma unroll
                for (int rr = 0; rr < 8; ++rr) {
                    a[rr] = fmaf(w00[rr][i].x, hv.x, a[rr]);
                    a[rr] = fmaf(w00[rr][i].y, hv.y, a[rr]);
                    a[rr] = fmaf(w00[rr][i].z, hv.z, a[rr]);
                    a[rr] = fmaf(w00[rr][i].w, hv.w, a[rr]);
                }
            }
#pragma unroll
            for (int off = 1; off <= 8; off <<= 1) {
#pragma unroll
                for (int rr = 0; rr < 8; ++rr)
                    a[rr] += __shfl_xor(a[rr], off, 64);
            }
            float pre = a[0];
#pragma unroll
            for (int rr = 1; rr < 8; ++rr) pre = (rsel == rr) ? a[rr] : pre;

            const float hv_new = tanhf(uval + lds_C[myrow] + pre);
            __syncthreads();                               // A (reads done)
            if (c16 < 8) {
                lds_h[myrow] = hv_new;
                h0p[myrow + (myrow >> 4) * 4] = hv_new;
                if (b < 2 && (myrow >> 7) == b)
                    lds_ring[t % 3][myrow & 127] = hv_new;
            }
            if (b >= 2 && tid < 32)   // rest slices unchanged at odd steps
                *(float4*)(&lds_ring[t % 3][4 * tid]) =
                    *(const float4*)(&lds_ring[(t + 2) % 3][4 * tid]);
            if (t < T_STEPS) {
                if (tid < 64) *(float4*)(lds_u0 + 4 * tid) = pf0;
                if (tid >= 64 && tid < 64 + 28) {
                    const int idx = tid - 64;
                    *(float4*)(lds_ur + (idx >> 2) * RPM + 4 * (idx & 3)) = pfr;
                }
            }
            __syncthreads();                               // B (end)
        }
    }

    // ---- flush the last two delayed rows: h(T-1) -> row T-2, h(T) -> row T-1
    __syncthreads();
    if (tid < 32) {
        *(float4*)(out + (size_t)(T_STEPS - 2) * HID + 128 * b + 4 * tid) =
            *(const float4*)(&lds_ring[(T_STEPS - 1) % 3][4 * tid]);
        *(float4*)(out + (size_t)(T_STEPS - 1) * HID + 128 * b + 4 * tid) =
            *(const float4*)(&lds_ring[T_STEPS % 3][4 * tid]);
    }
}

// ---------------------------------------------------------------------------
extern "C" void kernel_launch(void* const* d_in, const int* in_sizes, int n_in,
                              void* d_out, int out_size, void* d_ws, size_t ws_size,
                              hipStream_t stream) {
    const float* x   = (const float*)d_in[0];
    const float* Wih = (const float*)d_in[1];
    const float* Whh = (const float*)d_in[2];
    const float* bih = (const float*)d_in[3];
    const float* bhh = (const float*)d_in[4];
    float* out = (float*)d_out;
    unsigned long long* comm = (unsigned long long*)d_ws;

    // packet tags must start at 0 (t runs 1..4096):
    // 2 banks x (1792 h + 4096 partial) x 8B = 94.2 KB of workspace
    hipMemsetAsync(d_ws, 0,
                   (2 * NSLOT7 + 2 * NPART) * sizeof(unsigned long long),
                   stream);

    dim3 g1(HID / BN, T_STEPS / BM);        // (16, 32)
    gemm_u<<<g1, 256, 0, stream>>>(x, Wih, bih, bhh, out);
    cwrnn_rec<<<NBLK, NTHR, 0, stream>>>(out, Whh, comm);
}